// Round 6
// baseline (70.743 us; speedup 1.0000x reference)
//
#include <hip/hip_runtime.h>
#include <math.h>

// Output = relu(relu(h2[t=6]) @ Wlin^T + b) -> only 7 LSTM steps matter.
//
// R6: SINGLE-WAVE blocks — no inter-wave synchronization at all.
// Evidence R1-R5: in-loop LDS/VALU counts and weight-load coalescing all
// failed to move dur; every added barrier-separated phase added time ->
// multi-wave phase-latency bound. Fix: block = 1 wave (64 threads), 2 batch
// elems/wave, 2048 blocks (8 waves/CU). __syncthreads() on a single-wave
// block is a no-op barrier (no partner waves, no skew); h1/h2 round-trip
// through wave-private LDS ordered by in-wave program order.
//
// Lane map: q = tid&3 (gate i,f,g,o), u = tid>>2 (units 0..15 primary).
// Units 16..19 = "secondary" rows su=16+(u&3), computed redundantly by all
// quads (uniform issue, no divergence), written back by the u<4 quads only.
// Weights in registers, rotated chunk order for the quad-DPP rotation dot.

constexpr int kT = 7;
constexpr int kI = 23;
constexpr int kH = 20;
constexpr int kE = 2;      // batch elems per wave
constexpr int kThreads = 64;

__device__ __forceinline__ float sigm(float v) {
    return __builtin_amdgcn_rcpf(1.0f + __builtin_amdgcn_exp2f(v * -1.44269504f));
}
__device__ __forceinline__ float tanh_(float v) {
    return 1.0f - 2.0f * __builtin_amdgcn_rcpf(__builtin_amdgcn_exp2f(v * 2.88539008f) + 1.0f);
}
template<int J>
__device__ __forceinline__ float qb(float v) {   // broadcast quad lane J
    return __int_as_float(__builtin_amdgcn_mov_dpp(__float_as_int(v), J * 0x55, 0xF, 0xF, true));
}
__device__ __forceinline__ float rotl(float v) { // lane q <- lane (q+1)&3
    return __int_as_float(__builtin_amdgcn_mov_dpp(__float_as_int(v), 0x39, 0xF, 0xF, true));
}
__device__ __forceinline__ float4 rot4(float4 v) {
    return make_float4(rotl(v.x), rotl(v.y), rotl(v.z), rotl(v.w));
}
__device__ __forceinline__ void lstm_update(float a, float& c, float& h) {
    const float gi = qb<0>(a), gf = qb<1>(a), gg = qb<2>(a), go = qb<3>(a);
    c = sigm(gf) * c + sigm(gi) * tanh_(gg);
    h = sigm(go) * tanh_(c);
}

// dot of one 20-float LDS row (24-stride) with TWO rotated weight sets.
#define DOT_STEP4(o)                                                 \
    p0 = fmaf(wp[o+0], v.x, p0); p1 = fmaf(wp[o+1], v.y, p1);        \
    s0 = fmaf(ws[o+0], v.x, s0); s1 = fmaf(ws[o+1], v.y, s1);        \
    p0 = fmaf(wp[o+2], v.z, p0); p1 = fmaf(wp[o+3], v.w, p1);        \
    s0 = fmaf(ws[o+2], v.z, s0); s1 = fmaf(ws[o+3], v.w, s1);

__device__ __forceinline__ void dot20x2(const float* __restrict__ row,
                                        const float* wp, const float* ws,
                                        int q4, float& rp, float& rs)
{
    float4 v = *reinterpret_cast<const float4*>(row + q4);
    float p0 = 0.f, p1 = 0.f, s0 = 0.f, s1 = 0.f;
    DOT_STEP4(0)  v = rot4(v);
    DOT_STEP4(4)  v = rot4(v);
    DOT_STEP4(8)  v = rot4(v);
    DOT_STEP4(12)
    const float4 t = *reinterpret_cast<const float4*>(row + 16);
    p0 = fmaf(wp[16], t.x, p0); p1 = fmaf(wp[17], t.y, p1);
    s0 = fmaf(ws[16], t.x, s0); s1 = fmaf(ws[17], t.y, s1);
    p0 = fmaf(wp[18], t.z, p0); p1 = fmaf(wp[19], t.w, p1);
    s0 = fmaf(ws[18], t.z, s0); s1 = fmaf(ws[19], t.w, s1);
    rp = p0 + p1; rs = s0 + s1;
}

__device__ __forceinline__ void dot24x2(const float* __restrict__ row,
                                        const float* wp, const float* ws,
                                        int q4, float& rp, float& rs)
{
    float4 v = *reinterpret_cast<const float4*>(row + q4);
    float p0 = 0.f, p1 = 0.f, s0 = 0.f, s1 = 0.f;
    DOT_STEP4(0)  v = rot4(v);
    DOT_STEP4(4)  v = rot4(v);
    DOT_STEP4(8)  v = rot4(v);
    DOT_STEP4(12)
    const float4 t4 = *reinterpret_cast<const float4*>(row + 16);
    p0 = fmaf(wp[16], t4.x, p0); p1 = fmaf(wp[17], t4.y, p1);
    s0 = fmaf(ws[16], t4.x, s0); s1 = fmaf(ws[17], t4.y, s1);
    p0 = fmaf(wp[18], t4.z, p0); p1 = fmaf(wp[19], t4.w, p1);
    s0 = fmaf(ws[18], t4.z, s0); s1 = fmaf(ws[19], t4.w, s1);
    const float4 t5 = *reinterpret_cast<const float4*>(row + 20);
    p0 = fmaf(wp[20], t5.x, p0); p1 = fmaf(wp[21], t5.y, p1);
    s0 = fmaf(ws[20], t5.x, s0); s1 = fmaf(ws[21], t5.y, s1);
    p0 = fmaf(wp[22], t5.z, p0); p1 = fmaf(wp[23], t5.w, p1);
    s0 = fmaf(ws[22], t5.z, s0); s1 = fmaf(ws[23], t5.w, s1);
    rp = p0 + p1; rs = s0 + s1;
}

__global__ __launch_bounds__(kThreads, 2) void lstm7_kernel(
    const float* __restrict__ x,
    const float* __restrict__ h0,
    const float* __restrict__ c0,
    const float* __restrict__ Wih0,
    const float* __restrict__ Whh0,
    const float* __restrict__ bih0,
    const float* __restrict__ bhh0,
    const float* __restrict__ Wih1,
    const float* __restrict__ Whh1,
    const float* __restrict__ bih1,
    const float* __restrict__ bhh1,
    const float* __restrict__ Wlin,
    const float* __restrict__ blin,
    float* __restrict__ out,
    int B)
{
    __shared__ __align__(16) float xL[kE][kT][24];   // [e][t][k], pad>=23 -> 0
    __shared__ __align__(16) float h1S[kE][24];      // [e][u]
    __shared__ __align__(16) float h2S[kE][24];

    const int tid = threadIdx.x;
    const int b0  = blockIdx.x * kE;
    const int q   = tid & 3;
    const int u   = tid >> 2;          // 0..15 (primary unit)
    const int su  = 16 + (u & 3);      // secondary unit 16..19
    const int gp  = q * kH + u;        // primary gate row (pytorch i,f,g,o)
    const int gs  = q * kH + su;       // secondary gate row
    const int q4  = q * 4;

    // ---- stage x (2 elems x 7 t x 24, pad = 0) ----
    for (int idx = tid; idx < kE * kT * 24; idx += kThreads) {
        const int e = idx / (kT * 24);
        const int r = idx % (kT * 24);
        const int t = r / 24;
        const int i = r % 24;
        xL[e][t][i] = (i < kI) ? x[((size_t)t * B + b0 + e) * kI + i] : 0.0f;
    }
    // ---- initial h ----
    if (tid < kE * kH) {
        const int e = tid / kH, uu = tid % kH;
        h1S[e][uu] = h0[(size_t)(b0 + e) * kH + uu];
        h2S[e][uu] = h0[((size_t)B + b0 + e) * kH + uu];
    }
    __syncthreads();  // single-wave: compiles to a trivial barrier

    // ---- xg = bias1 + W_ih0 . x (primary + secondary rows), into registers ----
    float xgp0[kT], xgp1[kT], xgs0[kT], xgs1[kT];
    {
        float wAp[24], wAs[24];
        const float* Ap = Wih0 + gp * kI;   // rows are 4B-aligned only -> scalar
        const float* As = Wih0 + gs * kI;
#pragma unroll
        for (int r = 0; r < 4; ++r) {
            const int c = (q + r) & 3;
#pragma unroll
            for (int j = 0; j < 4; ++j) {
                wAp[4*r + j] = Ap[4*c + j];
                wAs[4*r + j] = As[4*c + j];
            }
        }
#pragma unroll
        for (int j = 0; j < 7; ++j) { wAp[16 + j] = Ap[16 + j]; wAs[16 + j] = As[16 + j]; }
        wAp[23] = 0.0f; wAs[23] = 0.0f;
        const float b1p = bih0[gp] + bhh0[gp];
        const float b1s = bih0[gs] + bhh0[gs];
#pragma unroll
        for (int t = 0; t < kT; ++t) {
            float dp, ds;
            dot24x2(&xL[0][t][0], wAp, wAs, q4, dp, ds);
            xgp0[t] = b1p + dp; xgs0[t] = b1s + ds;
            dot24x2(&xL[1][t][0], wAp, wAs, q4, dp, ds);
            xgp1[t] = b1p + dp; xgs1[t] = b1s + ds;
        }
    }

    // ---- in-loop weights (rotated chunk order; rows 16B-aligned) ----
    float wBp[kH], wCp[kH], wDp[kH], wBs[kH], wCs[kH], wDs[kH];
    {
        const float4* PB = reinterpret_cast<const float4*>(Whh0 + gp * kH);
        const float4* PC = reinterpret_cast<const float4*>(Wih1 + gp * kH);
        const float4* PD = reinterpret_cast<const float4*>(Whh1 + gp * kH);
        const float4* SB = reinterpret_cast<const float4*>(Whh0 + gs * kH);
        const float4* SC = reinterpret_cast<const float4*>(Wih1 + gs * kH);
        const float4* SD = reinterpret_cast<const float4*>(Whh1 + gs * kH);
#pragma unroll
        for (int r = 0; r < 4; ++r) {
            const int c = (q + r) & 3;
            const float4 vb = PB[c], vc = PC[c], vd = PD[c];
            const float4 ub = SB[c], uc = SC[c], ud = SD[c];
            wBp[4*r+0]=vb.x; wBp[4*r+1]=vb.y; wBp[4*r+2]=vb.z; wBp[4*r+3]=vb.w;
            wCp[4*r+0]=vc.x; wCp[4*r+1]=vc.y; wCp[4*r+2]=vc.z; wCp[4*r+3]=vc.w;
            wDp[4*r+0]=vd.x; wDp[4*r+1]=vd.y; wDp[4*r+2]=vd.z; wDp[4*r+3]=vd.w;
            wBs[4*r+0]=ub.x; wBs[4*r+1]=ub.y; wBs[4*r+2]=ub.z; wBs[4*r+3]=ub.w;
            wCs[4*r+0]=uc.x; wCs[4*r+1]=uc.y; wCs[4*r+2]=uc.z; wCs[4*r+3]=uc.w;
            wDs[4*r+0]=ud.x; wDs[4*r+1]=ud.y; wDs[4*r+2]=ud.z; wDs[4*r+3]=ud.w;
        }
        const float4 tb = PB[4], tc = PC[4], td = PD[4];
        const float4 rb = SB[4], rc = SC[4], rd = SD[4];
        wBp[16]=tb.x; wBp[17]=tb.y; wBp[18]=tb.z; wBp[19]=tb.w;
        wCp[16]=tc.x; wCp[17]=tc.y; wCp[18]=tc.z; wCp[19]=tc.w;
        wDp[16]=td.x; wDp[17]=td.y; wDp[18]=td.z; wDp[19]=td.w;
        wBs[16]=rb.x; wBs[17]=rb.y; wBs[18]=rb.z; wBs[19]=rb.w;
        wCs[16]=rc.x; wCs[17]=rc.y; wCs[18]=rc.z; wCs[19]=rc.w;
        wDs[16]=rd.x; wDs[17]=rd.y; wDs[18]=rd.z; wDs[19]=rd.w;
    }
    const float b2p = bih1[gp] + bhh1[gp];
    const float b2s = bih1[gs] + bhh1[gs];

    // ---- c state: primary unit u and secondary unit su, both elems ----
    float c1p0 = c0[(size_t)(b0 + 0) * kH + u];
    float c1p1 = c0[(size_t)(b0 + 1) * kH + u];
    float c2p0 = c0[((size_t)B + b0 + 0) * kH + u];
    float c2p1 = c0[((size_t)B + b0 + 1) * kH + u];
    float c1s0 = c0[(size_t)(b0 + 0) * kH + su];
    float c1s1 = c0[(size_t)(b0 + 1) * kH + su];
    float c2s0 = c0[((size_t)B + b0 + 0) * kH + su];
    float c2s1 = c0[((size_t)B + b0 + 1) * kH + su];

    // ---- 7 timesteps; all sync is wave-internal ----
#pragma unroll
    for (int t = 0; t < kT; ++t) {
        // layer 1: gates = xg + W_hh0 . h1(old)
        float dp0, ds0, dp1, ds1;
        dot20x2(&h1S[0][0], wBp, wBs, q4, dp0, ds0);
        dot20x2(&h1S[1][0], wBp, wBs, q4, dp1, ds1);
        float h1p0, h1p1, h1s0, h1s1;
        lstm_update(xgp0[t] + dp0, c1p0, h1p0);
        lstm_update(xgp1[t] + dp1, c1p1, h1p1);
        lstm_update(xgs0[t] + ds0, c1s0, h1s0);
        lstm_update(xgs1[t] + ds1, c1s1, h1s1);
        if (q == 0) {
            h1S[0][u] = h1p0; h1S[1][u] = h1p1;
            if (u < 4) { h1S[0][su] = h1s0; h1S[1][su] = h1s1; }
        }
        __syncthreads();

        // layer 2: gates = b2 + W_ih1 . h1(new) + W_hh1 . h2(old)
        float ap0, as0, ap1, as1, bp0, bs0, bp1, bs1;
        dot20x2(&h1S[0][0], wCp, wCs, q4, ap0, as0);
        dot20x2(&h2S[0][0], wDp, wDs, q4, bp0, bs0);
        dot20x2(&h1S[1][0], wCp, wCs, q4, ap1, as1);
        dot20x2(&h2S[1][0], wDp, wDs, q4, bp1, bs1);
        float h2p0, h2p1, h2s0, h2s1;
        lstm_update(b2p + ap0 + bp0, c2p0, h2p0);
        lstm_update(b2p + ap1 + bp1, c2p1, h2p1);
        lstm_update(b2s + as0 + bs0, c2s0, h2s0);
        lstm_update(b2s + as1 + bs1, c2s1, h2s1);
        if (q == 0) {
            h2S[0][u] = h2p0; h2S[1][u] = h2p1;
            if (u < 4) { h2S[0][su] = h2s0; h2S[1][su] = h2s1; }
        }
        __syncthreads();
    }

    // ---- linear head on final h2 ----
    if (tid < kE) {
        float acc = blin[0];
#pragma unroll
        for (int uu = 0; uu < kH; ++uu) {
            acc = fmaf(fmaxf(h2S[tid][uu], 0.0f), Wlin[uu], acc);
        }
        out[b0 + tid] = fmaxf(acc, 0.0f);
    }
}

extern "C" void kernel_launch(void* const* d_in, const int* in_sizes, int n_in,
                              void* d_out, int out_size, void* d_ws, size_t ws_size,
                              hipStream_t stream) {
    const float* x    = (const float*)d_in[0];
    const float* h0   = (const float*)d_in[1];
    const float* c0   = (const float*)d_in[2];
    const float* Wih0 = (const float*)d_in[3];
    const float* Whh0 = (const float*)d_in[4];
    const float* bih0 = (const float*)d_in[5];
    const float* bhh0 = (const float*)d_in[6];
    const float* Wih1 = (const float*)d_in[7];
    const float* Whh1 = (const float*)d_in[8];
    const float* bih1 = (const float*)d_in[9];
    const float* bhh1 = (const float*)d_in[10];
    const float* Wlin = (const float*)d_in[11];
    const float* blin = (const float*)d_in[12];
    float* out = (float*)d_out;

    const int B = in_sizes[1] / (2 * kH);  // h0 is [2, B, 20]
    const int blocks = B / kE;             // 4096/2 = 2048

    hipLaunchKernelGGL(lstm7_kernel, dim3(blocks), dim3(kThreads), 0, stream,
                       x, h0, c0, Wih0, Whh0, bih0, bhh0,
                       Wih1, Whh1, bih1, bhh1, Wlin, blin, out, B);
}

// Round 7
// 39.440 us; speedup vs baseline: 1.7937x; 1.7937x over previous
//
#include <hip/hip_runtime.h>
#include <math.h>

// Output = relu(relu(h2[t=6]) @ Wlin^T + b) -> only 7 LSTM steps matter.
//
// R7: two kernels.
//  A (1 block): build lane-slot-major weight pack in ws:
//     pack[slot][p] (float4), p in [0,80): q=p&3, u=p>>2, grow=q*20+u.
//     slots 0-5  : Wih0 row grow, plain chunks (c=4*slot), tail zero-padded
//     slots 6-10 : Whh0 row grow, ROTATED chunks c=4*((q+r)&3), tail [16..20)
//     slots 11-15: Wih1 likewise, slots 16-20: Whh1 likewise
//     ws[6720+p] = bih0+bhh0 (bias1), ws[6800+p] = bih1+bhh1 (bias2)
//  B (512 x 320, R4's proven loop): weight prologue = 21 COALESCED b128 pack
//     loads (kills the ~11us 64-lane-divergent gather of R1/R4); xg phase
//     reads x via broadcast scalar loads (waves share the same 2 rows);
//     in-loop: quad-DPP rotation, 12 ds_read_b128 + 1 b64 per lane-step.

constexpr int kT  = 7;
constexpr int kI  = 23;
constexpr int kH  = 20;
constexpr int kG  = 80;
constexpr int kBT = 8;     // batch tile per block
constexpr int kThreads = 320;
constexpr int kGP = 10;    // xgS batch stride
constexpr int kSlots = 21; // pack float4-slots per p
constexpr int kB1Off = kSlots * kG * 4;      // 6720 floats
constexpr int kB2Off = kB1Off + kG;          // 6800

__device__ __forceinline__ float sigm(float v) {
    return __builtin_amdgcn_rcpf(1.0f + __builtin_amdgcn_exp2f(v * -1.44269504f));
}
__device__ __forceinline__ float tanh_(float v) {
    return 1.0f - 2.0f * __builtin_amdgcn_rcpf(__builtin_amdgcn_exp2f(v * 2.88539008f) + 1.0f);
}
template<int J>
__device__ __forceinline__ float qb(float v) {   // broadcast quad lane J
    return __int_as_float(__builtin_amdgcn_mov_dpp(__float_as_int(v), J * 0x55, 0xF, 0xF, true));
}
__device__ __forceinline__ float rotl(float v) { // lane q <- lane (q+1)&3
    return __int_as_float(__builtin_amdgcn_mov_dpp(__float_as_int(v), 0x39, 0xF, 0xF, true));
}
__device__ __forceinline__ float4 rot4(float4 v) {
    return make_float4(rotl(v.x), rotl(v.y), rotl(v.z), rotl(v.w));
}
__device__ __forceinline__ void lstm_update(float a, float& c, float& h) {
    const float gi = qb<0>(a), gf = qb<1>(a), gg = qb<2>(a), go = qb<3>(a);
    c = sigm(gf) * c + sigm(gi) * tanh_(gg);
    h = sigm(go) * tanh_(c);
}

// 20-float LDS row dot rotated weights w[0..19] (R4-proven)
__device__ __forceinline__ float dot20(const float* __restrict__ row, const float* w, int q4) {
    float4 v = *reinterpret_cast<const float4*>(row + q4);
    float a0 = 0.f, a1 = 0.f;
    a0 = fmaf(w[0],  v.x, a0); a1 = fmaf(w[1],  v.y, a1);
    a0 = fmaf(w[2],  v.z, a0); a1 = fmaf(w[3],  v.w, a1);
    v = rot4(v);
    a0 = fmaf(w[4],  v.x, a0); a1 = fmaf(w[5],  v.y, a1);
    a0 = fmaf(w[6],  v.z, a0); a1 = fmaf(w[7],  v.w, a1);
    v = rot4(v);
    a0 = fmaf(w[8],  v.x, a0); a1 = fmaf(w[9],  v.y, a1);
    a0 = fmaf(w[10], v.z, a0); a1 = fmaf(w[11], v.w, a1);
    v = rot4(v);
    a0 = fmaf(w[12], v.x, a0); a1 = fmaf(w[13], v.y, a1);
    a0 = fmaf(w[14], v.z, a0); a1 = fmaf(w[15], v.w, a1);
    const float4 t = *reinterpret_cast<const float4*>(row + 16);
    a0 = fmaf(w[16], t.x, a0); a1 = fmaf(w[17], t.y, a1);
    a0 = fmaf(w[18], t.z, a0); a1 = fmaf(w[19], t.w, a1);
    return a0 + a1;
}

// ---------------- Kernel A: weight pack (1 block, 256 threads) ----------------
__global__ void pack_kernel(const float* __restrict__ Wih0,
                            const float* __restrict__ Whh0,
                            const float* __restrict__ bih0,
                            const float* __restrict__ bhh0,
                            const float* __restrict__ Wih1,
                            const float* __restrict__ Whh1,
                            const float* __restrict__ bih1,
                            const float* __restrict__ bhh1,
                            float* __restrict__ ws)
{
    const int tid = threadIdx.x;
    for (int idx = tid; idx < kSlots * kG; idx += 256) {
        const int slot = idx / kG, p = idx % kG;
        const int q = p & 3, u = p >> 2, g = q * kH + u;
        float4 v;
        if (slot < 6) {                       // Wih0 row, plain chunk order
            const float* W = Wih0 + g * kI;
            const int c = slot * 4;
            v.x = W[c];
            v.y = (c + 1 < kI) ? W[c + 1] : 0.0f;
            v.z = (c + 2 < kI) ? W[c + 2] : 0.0f;
            v.w = (c + 3 < kI) ? W[c + 3] : 0.0f;
        } else {                              // rotated chunks for quad-DPP dot
            const int m = (slot - 6) / 5, r = (slot - 6) % 5;
            const float* W = (m == 0 ? Whh0 : (m == 1 ? Wih1 : Whh1)) + g * kH;
            const int c = (r < 4) ? 4 * ((q + r) & 3) : 16;
            v = make_float4(W[c], W[c + 1], W[c + 2], W[c + 3]);
        }
        reinterpret_cast<float4*>(ws)[idx] = v;
    }
    if (tid < 2 * kG) {
        const int p = tid % kG, g = (p & 3) * kH + (p >> 2);
        ws[kB1Off + tid] = (tid < kG) ? (bih0[g] + bhh0[g]) : (bih1[g] + bhh1[g]);
    }
}

// ---------------- Kernel B: 7-step fused LSTM ----------------
__global__ __launch_bounds__(kThreads, 2) void lstm7_kernel(
    const float* __restrict__ x,
    const float* __restrict__ h0,
    const float* __restrict__ c0,
    const float* __restrict__ Wlin,
    const float* __restrict__ blin,
    const float* __restrict__ ws,
    float* __restrict__ out,
    int B)
{
    __shared__ __align__(16) float xgS[kT][kG][kGP];   // 22.4 KB
    __shared__ __align__(16) float h1S[2][kBT][kH];
    __shared__ __align__(16) float h2S[2][kBT][kH];

    const int tid = threadIdx.x;
    const int b0  = blockIdx.x * kBT;
    const int p   = tid % kG;
    const int q   = p & 3;
    const int u   = p >> 2;
    const int bp  = tid / kG;
    const int bb  = bp * 2;
    const int q4  = q * 4;

    // ---- initial h (buffer 0), coalesced ----
    if (tid < kBT * kH) {
        const int e = tid / kH, uu = tid % kH;
        h1S[0][e][uu] = h0[(size_t)(b0 + e) * kH + uu];
        h2S[0][e][uu] = h0[((size_t)B + b0 + e) * kH + uu];
    }

    const float4* pk = reinterpret_cast<const float4*>(ws);

    // ---- xg phase: wA from pack (coalesced), x via broadcast scalar loads ----
    {
        float wA[24];
#pragma unroll
        for (int j = 0; j < 6; ++j) {
            const float4 v = pk[j * kG + p];
            wA[4*j] = v.x; wA[4*j+1] = v.y; wA[4*j+2] = v.z; wA[4*j+3] = v.w;
        }
        const float bias1 = ws[kB1Off + p];
#pragma unroll
        for (int t = 0; t < kT; ++t) {
#pragma unroll
            for (int e = 0; e < 2; ++e) {
                const float* xr = x + ((size_t)t * B + b0 + bb + e) * kI;
                float a0 = bias1, a1 = 0.f;
#pragma unroll
                for (int i = 0; i < kI; i += 2) {
                    a0 = fmaf(wA[i], xr[i], a0);
                    if (i + 1 < kI) a1 = fmaf(wA[i + 1], xr[i + 1], a1);
                }
                xgS[t][p][bb + e] = a0 + a1;
            }
        }
    }

    // ---- in-loop weights from pack (coalesced, rotated order) ----
    float wB[kH], wC[kH], wD[kH];
#pragma unroll
    for (int j = 0; j < 5; ++j) {
        const float4 vb = pk[(6 + j)  * kG + p];
        const float4 vc = pk[(11 + j) * kG + p];
        const float4 vd = pk[(16 + j) * kG + p];
        wB[4*j]=vb.x; wB[4*j+1]=vb.y; wB[4*j+2]=vb.z; wB[4*j+3]=vb.w;
        wC[4*j]=vc.x; wC[4*j+1]=vc.y; wC[4*j+2]=vc.z; wC[4*j+3]=vc.w;
        wD[4*j]=vd.x; wD[4*j+1]=vd.y; wD[4*j+2]=vd.z; wD[4*j+3]=vd.w;
    }
    const float bias2 = ws[kB2Off + p];
    float c1x = c0[(size_t)(b0 + bb) * kH + u];
    float c1y = c0[(size_t)(b0 + bb + 1) * kH + u];
    float c2x = c0[((size_t)B + b0 + bb) * kH + u];
    float c2y = c0[((size_t)B + b0 + bb + 1) * kH + u];

    __syncthreads();   // h staging visible; xgS is own-lane (no barrier needed)

    // ---- 7 timesteps, 2 layers, 2 barriers/step (R4-proven loop) ----
#pragma unroll
    for (int t = 0; t < kT; ++t) {
        const int rb = t & 1, wb = rb ^ 1;

        const float2 xg = *reinterpret_cast<const float2*>(&xgS[t][p][bb]);
        const float g0 = xg.x + dot20(&h1S[rb][bb][0],     wB, q4);
        const float g1 = xg.y + dot20(&h1S[rb][bb + 1][0], wB, q4);
        float h1x, h1y;
        lstm_update(g0, c1x, h1x);
        lstm_update(g1, c1y, h1y);
        if (q == 0) { h1S[wb][bb][u] = h1x; h1S[wb][bb + 1][u] = h1y; }
        __syncthreads();

        const float s0 = bias2 + dot20(&h1S[wb][bb][0],     wC, q4)
                               + dot20(&h2S[rb][bb][0],     wD, q4);
        const float s1 = bias2 + dot20(&h1S[wb][bb + 1][0], wC, q4)
                               + dot20(&h2S[rb][bb + 1][0], wD, q4);
        float h2x, h2y;
        lstm_update(s0, c2x, h2x);
        lstm_update(s1, c2y, h2y);
        if (q == 0) { h2S[wb][bb][u] = h2x; h2S[wb][bb + 1][u] = h2y; }
        __syncthreads();
    }

    // ---- linear head on h2 of t=6 (buffer 1) ----
    if (tid < kBT) {
        const int b = tid;
        float acc = blin[0];
#pragma unroll
        for (int uu = 0; uu < kH; ++uu) {
            acc = fmaf(fmaxf(h2S[1][b][uu], 0.0f), Wlin[uu], acc);
        }
        out[b0 + b] = fmaxf(acc, 0.0f);
    }
}

extern "C" void kernel_launch(void* const* d_in, const int* in_sizes, int n_in,
                              void* d_out, int out_size, void* d_ws, size_t ws_size,
                              hipStream_t stream) {
    const float* x    = (const float*)d_in[0];
    const float* h0   = (const float*)d_in[1];
    const float* c0   = (const float*)d_in[2];
    const float* Wih0 = (const float*)d_in[3];
    const float* Whh0 = (const float*)d_in[4];
    const float* bih0 = (const float*)d_in[5];
    const float* bhh0 = (const float*)d_in[6];
    const float* Wih1 = (const float*)d_in[7];
    const float* Whh1 = (const float*)d_in[8];
    const float* bih1 = (const float*)d_in[9];
    const float* bhh1 = (const float*)d_in[10];
    const float* Wlin = (const float*)d_in[11];
    const float* blin = (const float*)d_in[12];
    float* out = (float*)d_out;
    float* ws  = (float*)d_ws;

    const int B = in_sizes[1] / (2 * kH);  // h0 is [2, B, 20]
    const int blocks = B / kBT;            // 4096/8 = 512

    hipLaunchKernelGGL(pack_kernel, dim3(1), dim3(256), 0, stream,
                       Wih0, Whh0, bih0, bhh0, Wih1, Whh1, bih1, bhh1, ws);
    hipLaunchKernelGGL(lstm7_kernel, dim3(blocks), dim3(kThreads), 0, stream,
                       x, h0, c0, Wlin, blin, ws, out, B);
}

// Round 9
// 35.582 us; speedup vs baseline: 1.9881x; 1.1084x over previous
//
#include <hip/hip_runtime.h>
#include <math.h>

// Output = relu(relu(h2[t=6]) @ Wlin^T + b) -> only 7 LSTM steps matter.
//
// R9 = R8 with the indexing bug fixed: weight rows must be read as
// wL[grow] (grow = q*20+u, the pytorch gate row), NOT wL[p] (p = u*4+q).
//
// Structure: R4's proven loop (quad-DPP rotation, VGPR 84, no spill) +
// conflict-free LDS weight staging:
//  - wL[80][84]: row stride 84 floats = 336B = 21x16B (odd multiple of 16B)
//    -> divergent-row b128 redistribution reads hit all 32 banks evenly
//    (8 words/bank = hardware minimum for 64 lanes x 16B).
//  - all global reads coalesced element-order copies.

constexpr int kT  = 7;
constexpr int kI  = 23;
constexpr int kH  = 20;
constexpr int kG  = 80;
constexpr int kBT = 8;     // batch tile per block
constexpr int kThreads = 320;
constexpr int kGP = 10;    // xgS batch stride
constexpr int kWL = 84;    // wL row stride (floats), conflict-free
// wL row layout: [0..23] Wih0 (col23=0) | [24..43] Whh0 | [44..63] Wih1 | [64..83] Whh1

__device__ __forceinline__ float sigm(float v) {
    return __builtin_amdgcn_rcpf(1.0f + __builtin_amdgcn_exp2f(v * -1.44269504f));
}
__device__ __forceinline__ float tanh_(float v) {
    return 1.0f - 2.0f * __builtin_amdgcn_rcpf(__builtin_amdgcn_exp2f(v * 2.88539008f) + 1.0f);
}
template<int J>
__device__ __forceinline__ float qb(float v) {   // broadcast quad lane J
    return __int_as_float(__builtin_amdgcn_mov_dpp(__float_as_int(v), J * 0x55, 0xF, 0xF, true));
}
__device__ __forceinline__ float rotl(float v) { // lane q <- lane (q+1)&3
    return __int_as_float(__builtin_amdgcn_mov_dpp(__float_as_int(v), 0x39, 0xF, 0xF, true));
}
__device__ __forceinline__ float4 rot4(float4 v) {
    return make_float4(rotl(v.x), rotl(v.y), rotl(v.z), rotl(v.w));
}
__device__ __forceinline__ void lstm_update(float a, float& c, float& h) {
    const float gi = qb<0>(a), gf = qb<1>(a), gg = qb<2>(a), go = qb<3>(a);
    c = sigm(gf) * c + sigm(gi) * tanh_(gg);
    h = sigm(go) * tanh_(c);
}

// 20-float LDS row dot rotated weights w[0..19] (R4-proven; reads are wave
// broadcasts: only 4 distinct addresses per instruction)
__device__ __forceinline__ float dot20(const float* __restrict__ row, const float* w, int q4) {
    float4 v = *reinterpret_cast<const float4*>(row + q4);
    float a0 = 0.f, a1 = 0.f;
    a0 = fmaf(w[0],  v.x, a0); a1 = fmaf(w[1],  v.y, a1);
    a0 = fmaf(w[2],  v.z, a0); a1 = fmaf(w[3],  v.w, a1);
    v = rot4(v);
    a0 = fmaf(w[4],  v.x, a0); a1 = fmaf(w[5],  v.y, a1);
    a0 = fmaf(w[6],  v.z, a0); a1 = fmaf(w[7],  v.w, a1);
    v = rot4(v);
    a0 = fmaf(w[8],  v.x, a0); a1 = fmaf(w[9],  v.y, a1);
    a0 = fmaf(w[10], v.z, a0); a1 = fmaf(w[11], v.w, a1);
    v = rot4(v);
    a0 = fmaf(w[12], v.x, a0); a1 = fmaf(w[13], v.y, a1);
    a0 = fmaf(w[14], v.z, a0); a1 = fmaf(w[15], v.w, a1);
    const float4 t = *reinterpret_cast<const float4*>(row + 16);
    a0 = fmaf(w[16], t.x, a0); a1 = fmaf(w[17], t.y, a1);
    a0 = fmaf(w[18], t.z, a0); a1 = fmaf(w[19], t.w, a1);
    return a0 + a1;
}

// 24-float padded xS row dot rotated weights w[0..23] (pad/w[23] = 0)
__device__ __forceinline__ float dot24(const float* __restrict__ row, const float* w, int q4) {
    float4 v = *reinterpret_cast<const float4*>(row + q4);
    float a0 = 0.f, a1 = 0.f;
    a0 = fmaf(w[0],  v.x, a0); a1 = fmaf(w[1],  v.y, a1);
    a0 = fmaf(w[2],  v.z, a0); a1 = fmaf(w[3],  v.w, a1);
    v = rot4(v);
    a0 = fmaf(w[4],  v.x, a0); a1 = fmaf(w[5],  v.y, a1);
    a0 = fmaf(w[6],  v.z, a0); a1 = fmaf(w[7],  v.w, a1);
    v = rot4(v);
    a0 = fmaf(w[8],  v.x, a0); a1 = fmaf(w[9],  v.y, a1);
    a0 = fmaf(w[10], v.z, a0); a1 = fmaf(w[11], v.w, a1);
    v = rot4(v);
    a0 = fmaf(w[12], v.x, a0); a1 = fmaf(w[13], v.y, a1);
    a0 = fmaf(w[14], v.z, a0); a1 = fmaf(w[15], v.w, a1);
    const float4 t4 = *reinterpret_cast<const float4*>(row + 16);
    a0 = fmaf(w[16], t4.x, a0); a1 = fmaf(w[17], t4.y, a1);
    a0 = fmaf(w[18], t4.z, a0); a1 = fmaf(w[19], t4.w, a1);
    const float4 t5 = *reinterpret_cast<const float4*>(row + 20);
    a0 = fmaf(w[20], t5.x, a0); a1 = fmaf(w[21], t5.y, a1);
    a0 = fmaf(w[22], t5.z, a0); a1 = fmaf(w[23], t5.w, a1);
    return a0 + a1;
}

__global__ __launch_bounds__(kThreads, 2) void lstm7_kernel(
    const float* __restrict__ x,
    const float* __restrict__ h0,
    const float* __restrict__ c0,
    const float* __restrict__ Wih0,
    const float* __restrict__ Whh0,
    const float* __restrict__ bih0,
    const float* __restrict__ bhh0,
    const float* __restrict__ Wih1,
    const float* __restrict__ Whh1,
    const float* __restrict__ bih1,
    const float* __restrict__ bhh1,
    const float* __restrict__ Wlin,
    const float* __restrict__ blin,
    float* __restrict__ out,
    int B)
{
    __shared__ __align__(16) float xS[kT][kBT][24];    //  5.4 KB
    __shared__ __align__(16) float xgS[kT][kG][kGP];   // 22.4 KB
    __shared__ __align__(16) float h1S[2][kBT][kH];    //  1.3 KB
    __shared__ __align__(16) float h2S[2][kBT][kH];    //  1.3 KB
    __shared__ __align__(16) float wL[kG][kWL];        // 26.9 KB

    const int tid = threadIdx.x;
    const int b0  = blockIdx.x * kBT;
    const int p   = tid % kG;
    const int q   = p & 3;
    const int u   = p >> 2;
    const int grow = q * kH + u;       // pytorch gate-row (i,f,g,o)
    const int bp  = tid / kG;
    const int bb  = bp * 2;
    const int q4  = q * 4;

    // ================ coalesced staging ================
    for (int idx = tid; idx < kT * kBT * kI; idx += kThreads) {
        const int t = idx / (kBT * kI);
        const int r = idx % (kBT * kI);
        const int b = r / kI;
        const int i = r % kI;
        xS[t][b][i] = x[((size_t)t * B + b0 + b) * kI + i];
    }
    if (tid < kT * kBT) xS[tid / kBT][tid % kBT][kI] = 0.0f;
    if (tid < kBT * kH) {
        const int e = tid / kH, uu = tid % kH;
        h1S[0][e][uu] = h0[(size_t)(b0 + e) * kH + uu];
        h2S[0][e][uu] = h0[((size_t)B + b0 + e) * kH + uu];
    }
    for (int idx = tid; idx < kG * kI; idx += kThreads) {   // Wih0 -> cols 0..22
        wL[idx / kI][idx % kI] = Wih0[idx];
    }
    if (tid < kG) wL[tid][kI] = 0.0f;                       // col 23 = 0
    for (int idx = tid; idx < kG * kH; idx += kThreads) {   // 3 matrices, coalesced
        const int g = idx / kH, k = idx % kH;
        wL[g][24 + k] = Whh0[idx];
        wL[g][44 + k] = Wih1[idx];
        wL[g][64 + k] = Whh1[idx];
    }
    __syncthreads();

    const float* row = &wL[grow][0];   // <-- R8 bug was wL[p]

    // ---- xg phase: wA from wL (conflict-free b128), dot24 over xS -> xgS ----
    {
        float wA[24];
#pragma unroll
        for (int r = 0; r < 4; ++r) {
            const int c = (q + r) & 3;
            const float4 v = *reinterpret_cast<const float4*>(row + 4 * c);
            wA[4*r+0] = v.x; wA[4*r+1] = v.y; wA[4*r+2] = v.z; wA[4*r+3] = v.w;
        }
        const float4 t4 = *reinterpret_cast<const float4*>(row + 16);
        const float4 t5 = *reinterpret_cast<const float4*>(row + 20);
        wA[16] = t4.x; wA[17] = t4.y; wA[18] = t4.z; wA[19] = t4.w;
        wA[20] = t5.x; wA[21] = t5.y; wA[22] = t5.z; wA[23] = t5.w;  // col23 = 0
        const float bias1 = bih0[grow] + bhh0[grow];
#pragma unroll
        for (int t = 0; t < kT; ++t) {
            const float g0 = bias1 + dot24(&xS[t][bb][0],     wA, q4);
            const float g1 = bias1 + dot24(&xS[t][bb + 1][0], wA, q4);
            *reinterpret_cast<float2*>(&xgS[t][p][bb]) = make_float2(g0, g1);
        }
    }

    // ---- in-loop weights from wL (conflict-free b128, rotated chunk order) ----
    float wB[kH], wC[kH], wD[kH];
    {
#pragma unroll
        for (int r = 0; r < 4; ++r) {
            const int c4 = 4 * ((q + r) & 3);
            const float4 vb = *reinterpret_cast<const float4*>(row + 24 + c4);
            const float4 vc = *reinterpret_cast<const float4*>(row + 44 + c4);
            const float4 vd = *reinterpret_cast<const float4*>(row + 64 + c4);
            wB[4*r+0]=vb.x; wB[4*r+1]=vb.y; wB[4*r+2]=vb.z; wB[4*r+3]=vb.w;
            wC[4*r+0]=vc.x; wC[4*r+1]=vc.y; wC[4*r+2]=vc.z; wC[4*r+3]=vc.w;
            wD[4*r+0]=vd.x; wD[4*r+1]=vd.y; wD[4*r+2]=vd.z; wD[4*r+3]=vd.w;
        }
        const float4 tb = *reinterpret_cast<const float4*>(row + 40);
        const float4 tc = *reinterpret_cast<const float4*>(row + 60);
        const float4 td = *reinterpret_cast<const float4*>(row + 80);
        wB[16]=tb.x; wB[17]=tb.y; wB[18]=tb.z; wB[19]=tb.w;
        wC[16]=tc.x; wC[17]=tc.y; wC[18]=tc.z; wC[19]=tc.w;
        wD[16]=td.x; wD[17]=td.y; wD[18]=td.z; wD[19]=td.w;
    }
    const float bias2 = bih1[grow] + bhh1[grow];
    float c1x = c0[(size_t)(b0 + bb) * kH + u];
    float c1y = c0[(size_t)(b0 + bb + 1) * kH + u];
    float c2x = c0[((size_t)B + b0 + bb) * kH + u];
    float c2y = c0[((size_t)B + b0 + bb + 1) * kH + u];

    // ---- 7 timesteps, 2 layers, 2 barriers/step (R4-proven loop) ----
#pragma unroll
    for (int t = 0; t < kT; ++t) {
        const int rb = t & 1, wb = rb ^ 1;

        const float2 xg = *reinterpret_cast<const float2*>(&xgS[t][p][bb]);
        const float g0 = xg.x + dot20(&h1S[rb][bb][0],     wB, q4);
        const float g1 = xg.y + dot20(&h1S[rb][bb + 1][0], wB, q4);
        float h1x, h1y;
        lstm_update(g0, c1x, h1x);
        lstm_update(g1, c1y, h1y);
        if (q == 0) { h1S[wb][bb][u] = h1x; h1S[wb][bb + 1][u] = h1y; }
        __syncthreads();

        const float s0 = bias2 + dot20(&h1S[wb][bb][0],     wC, q4)
                               + dot20(&h2S[rb][bb][0],     wD, q4);
        const float s1 = bias2 + dot20(&h1S[wb][bb + 1][0], wC, q4)
                               + dot20(&h2S[rb][bb + 1][0], wD, q4);
        float h2x, h2y;
        lstm_update(s0, c2x, h2x);
        lstm_update(s1, c2y, h2y);
        if (q == 0) { h2S[wb][bb][u] = h2x; h2S[wb][bb + 1][u] = h2y; }
        __syncthreads();
    }

    // ---- linear head on h2 of t=6 (buffer 1) ----
    if (tid < kBT) {
        const int b = tid;
        float acc = blin[0];
#pragma unroll
        for (int uu = 0; uu < kH; ++uu) {
            acc = fmaf(fmaxf(h2S[1][b][uu], 0.0f), Wlin[uu], acc);
        }
        out[b0 + b] = fmaxf(acc, 0.0f);
    }
}

extern "C" void kernel_launch(void* const* d_in, const int* in_sizes, int n_in,
                              void* d_out, int out_size, void* d_ws, size_t ws_size,
                              hipStream_t stream) {
    const float* x    = (const float*)d_in[0];
    const float* h0   = (const float*)d_in[1];
    const float* c0   = (const float*)d_in[2];
    const float* Wih0 = (const float*)d_in[3];
    const float* Whh0 = (const float*)d_in[4];
    const float* bih0 = (const float*)d_in[5];
    const float* bhh0 = (const float*)d_in[6];
    const float* Wih1 = (const float*)d_in[7];
    const float* Whh1 = (const float*)d_in[8];
    const float* bih1 = (const float*)d_in[9];
    const float* bhh1 = (const float*)d_in[10];
    const float* Wlin = (const float*)d_in[11];
    const float* blin = (const float*)d_in[12];
    float* out = (float*)d_out;

    const int B = in_sizes[1] / (2 * kH);  // h0 is [2, B, 20]
    const int blocks = B / kBT;            // 4096/8 = 512

    hipLaunchKernelGGL(lstm7_kernel, dim3(blocks), dim3(kThreads), 0, stream,
                       x, h0, c0, Wih0, Whh0, bih0, bhh0,
                       Wih1, Whh1, bih1, bhh1, Wlin, blin, out, B);
}